// Round 20
// baseline (97.268 us; speedup 1.0000x reference)
//
#include <hip/hip_runtime.h>
#include <hip/hip_fp16.h>

#define HDIM 16
#define FIN 54
#define BSHIFT 7                  // 128 nodes per bucket
#define BNODES (1 << BSHIFT)      // 128
#define NBMAXB 800                // LDS bucket arrays (nb = 782)
#define NBBMAX 512                // max fill blocks supported
#define FBT 1024                  // threads in fill blocks
#define LST 512                   // threads in sort_gemm blocks
#define FPE 12544                 // LDS stage entries in fill (50 KB)
#define EBE 6272                  // compacted edge copy entries in sort (24.5 KB)
#define PADCOL 6144               // col slots per bucket (mean 4092 + 32 sigma)
#define GPAD 55                   // padded x-row stride in LDS (55 mod 32 = 23)

// ---------------------------------------------------------------------------
// fill: self-contained binning (R17-proven). Block owns binned[blk*per ..).
// ---------------------------------------------------------------------------
__global__ __launch_bounds__(FBT)
void fill_binned_kernel(const int* __restrict__ src, const int* __restrict__ dst,
                        int* __restrict__ lps, unsigned int* __restrict__ binned,
                        int E, int nb, int nbb, int per) {
    __shared__ unsigned int stage[FPE];     // 50 KB
    __shared__ int lh[NBMAXB], lcur[NBMAXB];
    __shared__ int ls[FBT];
    int blk = blockIdx.x;
    int s0 = blk * per;
    int s1 = min(E, s0 + per);
    int tot = s1 - s0;
    int t = threadIdx.x;

    for (int b = t; b < nb; b += FBT) lh[b] = 0;
    __syncthreads();
    // pass 1: histogram
    int idx = s0 + (t << 2);
    for (; idx + 3 < s1; idx += (FBT << 2)) {
        int4 d4 = *(const int4*)&dst[idx];
        atomicAdd(&lh[d4.x >> BSHIFT], 1);
        atomicAdd(&lh[d4.y >> BSHIFT], 1);
        atomicAdd(&lh[d4.z >> BSHIFT], 1);
        atomicAdd(&lh[d4.w >> BSHIFT], 1);
    }
    if (idx < s1) {
        int stop = min(idx + 4, s1);
        for (int e = idx; e < stop; ++e) atomicAdd(&lh[dst[e] >> BSHIFT], 1);
    }
    __syncthreads();
    // inclusive scan over buckets
    ls[t] = (t < nb) ? lh[t] : 0;
    __syncthreads();
    for (int d = 1; d < FBT; d <<= 1) {
        int v = (t >= d) ? ls[t - d] : 0;
        __syncthreads();
        ls[t] += v;
        __syncthreads();
    }
    if (t <= nb) {
        int excl = ls[t] - ((t < nb) ? lh[t] : 0);
        if (t < nb) lcur[t] = excl;
        lps[t * nbb + blk] = excl;          // row nb = total
    }
    __syncthreads();
    // pass 2: place into stage
    idx = s0 + (t << 2);
    for (; idx + 3 < s1; idx += (FBT << 2)) {
        int4 d4 = *(const int4*)&dst[idx];
        int4 v4 = *(const int4*)&src[idx];
        int p0 = atomicAdd(&lcur[d4.x >> BSHIFT], 1);
        int p1 = atomicAdd(&lcur[d4.y >> BSHIFT], 1);
        int p2 = atomicAdd(&lcur[d4.z >> BSHIFT], 1);
        int p3 = atomicAdd(&lcur[d4.w >> BSHIFT], 1);
        stage[p0] = ((unsigned int)v4.x << BSHIFT) | (unsigned int)(d4.x & (BNODES - 1));
        stage[p1] = ((unsigned int)v4.y << BSHIFT) | (unsigned int)(d4.y & (BNODES - 1));
        stage[p2] = ((unsigned int)v4.z << BSHIFT) | (unsigned int)(d4.z & (BNODES - 1));
        stage[p3] = ((unsigned int)v4.w << BSHIFT) | (unsigned int)(d4.w & (BNODES - 1));
    }
    if (idx < s1) {
        int stop = min(idx + 4, s1);
        for (int e = idx; e < stop; ++e) {
            int d = dst[e];
            int pos = atomicAdd(&lcur[d >> BSHIFT], 1);
            stage[pos] = ((unsigned int)src[e] << BSHIFT) | (unsigned int)(d & (BNODES - 1));
        }
    }
    __syncthreads();
    // flush verbatim (coalesced)
    for (int k = t; k < tot; k += FBT) binned[s0 + k] = stage[k];
}

// ---------------------------------------------------------------------------
// sort+gemm: single global pass over this bucket's cells.
//   S: cell-length prefix scan -> co[blk] (compact offsets), len
//   A': read cells ONCE -> hist atomics + compacted LDS copy ebuf
//   scan hist -> cs/ce/dinv (di in register)
//   B: placement from ebuf (all-LDS) into stage
//   C: flush stage -> col coalesced
//   D: reuse ubuf as xl/Wl; gemm tail -> hA fp16
// ---------------------------------------------------------------------------
__global__ __launch_bounds__(LST)
void sort_gemm_kernel(const unsigned int* __restrict__ binned,
                      const int* __restrict__ lps,
                      const float* __restrict__ x, const float* __restrict__ W1,
                      unsigned int* __restrict__ col, int* __restrict__ cs,
                      int* __restrict__ ce, float* __restrict__ dinv,
                      __half* __restrict__ hA,
                      int n, int nb, int nbb, int per) {
    __shared__ int st[NBBMAX], en[NBBMAX], co[NBBMAX];      // 6 KB
    __shared__ int hist[BNODES], scn[BNODES], cur[BNODES];  // 1.5 KB
    __shared__ unsigned int ebuf[EBE];                      // 24.5 KB compact copy
    __shared__ int lensh;
    __shared__ char ubuf[32768];                            // 32 KB phase buffer
    int* ls = (int*)ubuf;                                   // S: LST ints
    unsigned int* stage = (unsigned int*)ubuf;              // B/C: PADCOL u32
    float* xl = (float*)ubuf;                               // D: 128*55 f32
    float* Wl = (float*)(ubuf + BNODES * GPAD * 4);         // D: 54*16 f32

    int b = blockIdx.x;
    int t = threadIdx.x;
    int colbase = b * PADCOL;
    int row0 = b << BSHIFT;
    int nrows = min(BNODES, n - row0);

    for (int blk = t; blk < nbb; blk += LST) {
        st[blk] = lps[b * nbb + blk];
        en[blk] = lps[(b + 1) * nbb + blk];
    }
    if (t < BNODES) hist[t] = 0;
    __syncthreads();
    // --- S: prefix scan of cell lengths -> co, len ---
    ls[t] = (t < nbb) ? (en[t] - st[t]) : 0;
    __syncthreads();
    for (int d = 1; d < LST; d <<= 1) {
        int v = (t >= d) ? ls[t - d] : 0;
        __syncthreads();
        ls[t] += v;
        __syncthreads();
    }
    if (t < nbb) co[t] = ls[t] - (en[t] - st[t]);
    if (t == 0) lensh = ls[nbb - 1];
    __syncthreads();

    // --- A': single global pass: hist + compacted copy ---
    int g = t >> 4, l = t & 15;             // 32 groups of 16 lanes (~16/cell)
    for (int blk = g; blk < nbb; blk += (LST >> 4)) {
        int base = blk * per;
        int s = st[blk], e = en[blk], c = co[blk] - s;
        for (int k = s + l; k < e; k += 16) {
            unsigned int p = binned[base + k];
            int pos = c + k;
            if (pos < EBE) ebuf[pos] = p;
            atomicAdd(&hist[p & (BNODES - 1)], 1);
        }
    }
    __syncthreads();
    if (t < BNODES) scn[t] = hist[t];
    __syncthreads();
    for (int d = 1; d < BNODES; d <<= 1) {
        int v = (t < BNODES && t >= d) ? scn[t - d] : 0;
        __syncthreads();
        if (t < BNODES) scn[t] += v;
        __syncthreads();
    }
    float di = 0.0f;
    if (t < BNODES) {
        int excl = scn[t] - hist[t];
        cur[t] = excl;
        int node = row0 + t;
        di = rsqrtf((float)hist[t] + 1.0f);
        if (node < n) {
            cs[node] = colbase + excl;
            ce[node] = colbase + excl + hist[t];
            dinv[node] = di;
        }
    }
    __syncthreads();
    // --- B: placement from ebuf (all-LDS) ---
    int len = lensh;
    int lim = min(len, EBE);
    for (int k = t; k < lim; k += LST) {
        unsigned int p = ebuf[k];
        int pos = atomicAdd(&cur[p & (BNODES - 1)], 1);
        unsigned int sv = p >> BSHIFT;
        if (pos < PADCOL) stage[pos] = sv;
        else col[colbase + pos] = sv;       // statistically-never overflow
    }
    if (len > EBE) {                        // statistically-never: re-read tail
        for (int blk = g; blk < nbb; blk += (LST >> 4)) {
            int base = blk * per;
            int s = st[blk], e = en[blk], c = co[blk] - s;
            for (int k = s + l; k < e; k += 16) {
                if (c + k >= EBE) {
                    unsigned int p = binned[base + k];
                    int pos = atomicAdd(&cur[p & (BNODES - 1)], 1);
                    unsigned int sv = p >> BSHIFT;
                    if (pos < PADCOL) stage[pos] = sv;
                    else col[colbase + pos] = sv;
                }
            }
        }
    }
    __syncthreads();
    // --- C: coalesced flush ---
    int flen = scn[BNODES - 1];
    if (flen > PADCOL) flen = PADCOL;
    for (int k = t; k < flen; k += LST) col[colbase + k] = stage[k];
    __syncthreads();
    // --- D: reuse ubuf as xl/Wl; stage x + W1; gemm tail ---
    const float* xb = x + (size_t)row0 * FIN;
    int tot = nrows * FIN;
    for (int i4 = t; i4 < (tot >> 2); i4 += LST) {
        float4 v = ((const float4*)xb)[i4];
        int i = i4 << 2;
        int r = i / FIN;
        int c = i - r * FIN;
#pragma unroll
        for (int u = 0; u < 4; ++u) {
            int cc = c + u, rr = r;
            if (cc >= FIN) { cc -= FIN; ++rr; }
            xl[rr * GPAD + cc] = (&v.x)[u];
        }
    }
    for (int i = (tot & ~3) + t; i < tot; i += LST) {
        int r = i / FIN;
        xl[r * GPAD + (i - r * FIN)] = xb[i];
    }
    for (int k = t; k < FIN * HDIM; k += LST) Wl[k] = W1[k];
    __syncthreads();
    if (t < nrows) {
        const float* xr = &xl[t * GPAD];
        float acc[HDIM];
#pragma unroll
        for (int j = 0; j < HDIM; ++j) acc[j] = 0.0f;
#pragma unroll
        for (int k = 0; k < FIN; ++k) {
            float xv = xr[k];
#pragma unroll
            for (int j = 0; j < HDIM; ++j)
                acc[j] = fmaf(xv, Wl[k * HDIM + j], acc[j]);
        }
        __half2 hh[8];
#pragma unroll
        for (int j = 0; j < 8; ++j)
            hh[j] = __floats2half2_rn(di * acc[2 * j], di * acc[2 * j + 1]);
        uint4* yo = (uint4*)(hA + ((size_t)(row0 + t) << 4));
        yo[0] = *(uint4*)&hh[0];
        yo[1] = *(uint4*)&hh[4];
    }
}

// ---------------------------------------------------------------------------
// Gather: 8 lanes per node (2 halves x 4 quarters). hs fp16, L2-resident.
// ---------------------------------------------------------------------------
__device__ __forceinline__ float4 ld_h4(const __half* __restrict__ hsh,
                                        unsigned int node, int q) {
    uint2 u = *(const uint2*)(hsh + ((size_t)node << 4) + (q << 2));
    __half2 a = *(__half2*)&u.x;
    __half2 b = *(__half2*)&u.y;
    float2 fa = __half22float2(a);
    float2 fb = __half22float2(b);
    return make_float4(fa.x, fa.y, fb.x, fb.y);
}

template <bool FUSE_W2>
__global__ void gather_kernel(const unsigned int* __restrict__ col,
                              const int* __restrict__ cs, const int* __restrict__ ce,
                              const __half* __restrict__ hsh, const float* __restrict__ dinv,
                              const float* __restrict__ bias, const float* __restrict__ W2,
                              __half* __restrict__ outh, float4* __restrict__ out4, int n) {
    __shared__ float4 W2l[HDIM * 4];   // W2l[jj*4+q] = W2[jj][4q..4q+3]
    if constexpr (FUSE_W2) {
        for (int t = threadIdx.x; t < HDIM * 4; t += blockDim.x)
            W2l[t] = ((const float4*)W2)[t];
        __syncthreads();
    }
    int idx = blockIdx.x * blockDim.x + threadIdx.x;
    int i = idx >> 3;
    int sub = idx & 7;
    int q = sub & 3;
    int h = sub >> 2;
    if (i >= n) return;
    int k0 = cs[i], k1 = ce[i];

    float4 acc = (h == 0) ? ld_h4(hsh, (unsigned int)i, q)   // self-loop on half 0
                          : make_float4(0.f, 0.f, 0.f, 0.f);
    int k = k0 + h;
    for (; k + 14 < k1; k += 16) {
        unsigned int s[8];
#pragma unroll
        for (int u = 0; u < 8; ++u) s[u] = col[k + 2 * u];
        float4 hv[8];
#pragma unroll
        for (int u = 0; u < 8; ++u) hv[u] = ld_h4(hsh, s[u], q);
#pragma unroll
        for (int u = 0; u < 8; ++u) {
            acc.x += hv[u].x; acc.y += hv[u].y; acc.z += hv[u].z; acc.w += hv[u].w;
        }
    }
    for (; k + 6 < k1; k += 8) {
        unsigned int s[4];
#pragma unroll
        for (int u = 0; u < 4; ++u) s[u] = col[k + 2 * u];
        float4 hv[4];
#pragma unroll
        for (int u = 0; u < 4; ++u) hv[u] = ld_h4(hsh, s[u], q);
#pragma unroll
        for (int u = 0; u < 4; ++u) {
            acc.x += hv[u].x; acc.y += hv[u].y; acc.z += hv[u].z; acc.w += hv[u].w;
        }
    }
    for (; k < k1; k += 2) {
        float4 hv = ld_h4(hsh, col[k], q);
        acc.x += hv.x; acc.y += hv.y; acc.z += hv.z; acc.w += hv.w;
    }
    // combine the two halves (partner = lane ^ 4)
    acc.x += __shfl_xor(acc.x, 4);
    acc.y += __shfl_xor(acc.y, 4);
    acc.z += __shfl_xor(acc.z, 4);
    acc.w += __shfl_xor(acc.w, 4);

    float di = dinv[i];
    float4 b4 = ((const float4*)bias)[q];
    float4 r;
    r.x = fmaxf(fmaf(di, acc.x, b4.x), 0.0f);
    r.y = fmaxf(fmaf(di, acc.y, b4.y), 0.0f);
    r.z = fmaxf(fmaf(di, acc.z, b4.z), 0.0f);
    r.w = fmaxf(fmaf(di, acc.w, b4.w), 0.0f);

    if constexpr (FUSE_W2) {
        int lane = threadIdx.x & 63;
        int base = lane & ~7;              // node's first lane (h=0, q=0)
        float4 o = make_float4(0.f, 0.f, 0.f, 0.f);
#pragma unroll
        for (int p = 0; p < 4; ++p) {      // lane base+p holds r for jj = 4p..4p+3
            float rx = __shfl(r.x, base + p, 64);
            float ry = __shfl(r.y, base + p, 64);
            float rz = __shfl(r.z, base + p, 64);
            float rw = __shfl(r.w, base + p, 64);
            float4 w0 = W2l[(p * 4 + 0) * 4 + q];
            float4 w1 = W2l[(p * 4 + 1) * 4 + q];
            float4 w2 = W2l[(p * 4 + 2) * 4 + q];
            float4 w3 = W2l[(p * 4 + 3) * 4 + q];
            o.x = fmaf(rx, w0.x, fmaf(ry, w1.x, fmaf(rz, w2.x, fmaf(rw, w3.x, o.x))));
            o.y = fmaf(rx, w0.y, fmaf(ry, w1.y, fmaf(rz, w2.y, fmaf(rw, w3.y, o.y))));
            o.z = fmaf(rx, w0.z, fmaf(ry, w1.z, fmaf(rz, w2.z, fmaf(rw, w3.z, o.z))));
            o.w = fmaf(rx, w0.w, fmaf(ry, w1.w, fmaf(rz, w2.w, fmaf(rw, w3.w, o.w))));
        }
        if (h == 0) {
            __half2 o01 = __floats2half2_rn(di * o.x, di * o.y);
            __half2 o23 = __floats2half2_rn(di * o.z, di * o.w);
            uint2 pk;
            pk.x = *(unsigned int*)&o01;
            pk.y = *(unsigned int*)&o23;
            *(uint2*)(outh + ((size_t)i << 4) + (q << 2)) = pk;
        }
    } else {
        if (h == 0) out4[(size_t)i * 4 + q] = r;
    }
}

extern "C" void kernel_launch(void* const* d_in, const int* in_sizes, int n_in,
                              void* d_out, int out_size, void* d_ws, size_t ws_size,
                              hipStream_t stream) {
    const float* x  = (const float*)d_in[0];   // [n, 54]
    const int*   ei = (const int*)d_in[1];     // [2, E]
    const float* W1 = (const float*)d_in[2];   // [54, 16]
    const float* b1 = (const float*)d_in[3];   // [16]
    const float* W2 = (const float*)d_in[4];   // [16, 16]
    const float* b2 = (const float*)d_in[5];   // [16]
    float* out = (float*)d_out;

    const int E = in_sizes[1] / 2;             // 3,200,000
    const int n = in_sizes[0] / FIN;           // 100,000
    const int* src = ei;
    const int* dst = ei + E;
    const int nb = (n + BNODES - 1) >> BSHIFT; // 782 buckets

    // fill blocks: per-block range fits the 50 KB stage; 256 blocks, 16/cell
    int nbb = (E + 12499) / 12500;             // 256 for E = 3.2M
    if (nbb > NBBMAX) nbb = NBBMAX;
    int per = (((E + nbb - 1) / nbb) + 3) & ~3;  // 12500, multiple of 4, <= FPE

    char* w = (char*)d_ws;
    auto take = [&](size_t bytes) { char* p = w; w += (bytes + 255) & ~(size_t)255; return p; };
    float* dinv = (float*)take((size_t)n * 4);
    int*   lps  = (int*)take((size_t)(nb + 1) * nbb * 4);
    int*   cs   = (int*)take((size_t)n * 4);
    int*   ce   = (int*)take((size_t)n * 4);
    unsigned int* binned = (unsigned int*)take((size_t)nbb * per * 4);
    __half* hA  = (__half*)take((size_t)n * HDIM * 2);   // must NOT alias binned
    __half* hB  = (__half*)take((size_t)n * HDIM * 2);
    unsigned int* col = (unsigned int*)take((size_t)nb * PADCOL * 4);

    const int B = 256;

    // --- build: fill (self-scanned) -> sort+gemm (CSR + dinv + hA) ---
    fill_binned_kernel<<<nbb, FBT, 0, stream>>>(src, dst, lps, binned, E, nb, nbb, per);
    sort_gemm_kernel<<<nb, LST, 0, stream>>>(binned, lps, x, W1, col, cs, ce, dinv,
                                             hA, n, nb, nbb, per);

    // --- layer 1 gather + relu + fused @W2 (pre-scaled, fp16) -> hB ---
    gather_kernel<true><<<(n * 8 + B - 1) / B, B, 0, stream>>>(
        col, cs, ce, hA, dinv, b1, W2, hB, nullptr, n);

    // --- layer 2 gather + bias + relu -> out (f32) ---
    gather_kernel<false><<<(n * 8 + B - 1) / B, B, 0, stream>>>(
        col, cs, ce, hB, dinv, b2, nullptr, nullptr, (float4*)out, n);
}

// Round 21
// 90.146 us; speedup vs baseline: 1.0790x; 1.0790x over previous
//
#include <hip/hip_runtime.h>
#include <hip/hip_fp16.h>

#define HDIM 16
#define FIN 54
#define BSHIFT 7                  // 128 nodes per bucket
#define BNODES (1 << BSHIFT)      // 128
#define NBMAXB 800                // LDS bucket arrays (nb = 782)
#define NBBMAX 512                // max fill blocks supported
#define FBT 1024                  // threads in fill blocks
#define LST 512                   // threads in sort_gemm blocks
#define FPE 12544                 // LDS stage entries in fill (50 KB)
#define PADCOL 6144               // col slots per bucket (mean 4092 + 32 sigma)
#define GPAD 55                   // padded x-row stride in LDS (55 mod 32 = 23)

// ---------------------------------------------------------------------------
// fill: self-contained binning. Block owns binned[blk*per .. blk*per+tot).
//   pass1: LDS bucket histogram (int4 loads)
//   scan : LDS exclusive scan -> local offsets; emit lps[b][blk] (b<=nb)
//   pass2: place packed (src<<7|dstLow) into LDS stage via cursors
//   flush: stage -> binned verbatim (stage is already bucket-sorted locally)
// ---------------------------------------------------------------------------
__global__ __launch_bounds__(FBT)
void fill_binned_kernel(const int* __restrict__ src, const int* __restrict__ dst,
                        int* __restrict__ lps, unsigned int* __restrict__ binned,
                        int E, int nb, int nbb, int per) {
    __shared__ unsigned int stage[FPE];     // 50 KB
    __shared__ int lh[NBMAXB], lcur[NBMAXB];
    __shared__ int ls[FBT];
    int blk = blockIdx.x;
    int s0 = blk * per;
    int s1 = min(E, s0 + per);
    int tot = s1 - s0;
    int t = threadIdx.x;

    for (int b = t; b < nb; b += FBT) lh[b] = 0;
    __syncthreads();
    // pass 1: histogram
    int idx = s0 + (t << 2);
    for (; idx + 3 < s1; idx += (FBT << 2)) {
        int4 d4 = *(const int4*)&dst[idx];
        atomicAdd(&lh[d4.x >> BSHIFT], 1);
        atomicAdd(&lh[d4.y >> BSHIFT], 1);
        atomicAdd(&lh[d4.z >> BSHIFT], 1);
        atomicAdd(&lh[d4.w >> BSHIFT], 1);
    }
    if (idx < s1) {
        int stop = min(idx + 4, s1);
        for (int e = idx; e < stop; ++e) atomicAdd(&lh[dst[e] >> BSHIFT], 1);
    }
    __syncthreads();
    // inclusive scan over buckets
    ls[t] = (t < nb) ? lh[t] : 0;
    __syncthreads();
    for (int d = 1; d < FBT; d <<= 1) {
        int v = (t >= d) ? ls[t - d] : 0;
        __syncthreads();
        ls[t] += v;
        __syncthreads();
    }
    if (t <= nb) {
        int excl = ls[t] - ((t < nb) ? lh[t] : 0);
        if (t < nb) lcur[t] = excl;
        lps[t * nbb + blk] = excl;          // row nb = total
    }
    __syncthreads();
    // pass 2: place into stage
    idx = s0 + (t << 2);
    for (; idx + 3 < s1; idx += (FBT << 2)) {
        int4 d4 = *(const int4*)&dst[idx];
        int4 v4 = *(const int4*)&src[idx];
        int p0 = atomicAdd(&lcur[d4.x >> BSHIFT], 1);
        int p1 = atomicAdd(&lcur[d4.y >> BSHIFT], 1);
        int p2 = atomicAdd(&lcur[d4.z >> BSHIFT], 1);
        int p3 = atomicAdd(&lcur[d4.w >> BSHIFT], 1);
        stage[p0] = ((unsigned int)v4.x << BSHIFT) | (unsigned int)(d4.x & (BNODES - 1));
        stage[p1] = ((unsigned int)v4.y << BSHIFT) | (unsigned int)(d4.y & (BNODES - 1));
        stage[p2] = ((unsigned int)v4.z << BSHIFT) | (unsigned int)(d4.z & (BNODES - 1));
        stage[p3] = ((unsigned int)v4.w << BSHIFT) | (unsigned int)(d4.w & (BNODES - 1));
    }
    if (idx < s1) {
        int stop = min(idx + 4, s1);
        for (int e = idx; e < stop; ++e) {
            int d = dst[e];
            int pos = atomicAdd(&lcur[d >> BSHIFT], 1);
            stage[pos] = ((unsigned int)src[e] << BSHIFT) | (unsigned int)(d & (BNODES - 1));
        }
    }
    __syncthreads();
    // flush verbatim (coalesced)
    for (int k = t; k < tot; k += FBT) binned[s0 + k] = stage[k];
}

// ---------------------------------------------------------------------------
// sort+gemm (R17-proven): bucket b's edges in cells binned[blk*per+st..en).
//   A: per-node histogram -> scan -> cs/ce/dinv (di kept in register)
//   B: placement into LDS stage (coalesced-flush pattern)
//   C: flush stage -> col[colbase..] coalesced
//   D: reuse stage LDS as xl/Wl; stage x rows + W1; gemm tail -> hA fp16
// hA must NOT alias binned (read and write overlap in this kernel).
// ---------------------------------------------------------------------------
__global__ __launch_bounds__(LST)
void sort_gemm_kernel(const unsigned int* __restrict__ binned,
                      const int* __restrict__ lps,
                      const float* __restrict__ x, const float* __restrict__ W1,
                      unsigned int* __restrict__ col, int* __restrict__ cs,
                      int* __restrict__ ce, float* __restrict__ dinv,
                      __half* __restrict__ hA,
                      int n, int nb, int nbb, int per) {
    __shared__ int st[NBBMAX], en[NBBMAX];                  // 4 KB
    __shared__ int hist[BNODES], scn[BNODES], cur[BNODES];  // 1.5 KB
    __shared__ char ubuf[32768];                            // 32 KB shared phase buffer
    unsigned int* stage = (unsigned int*)ubuf;              // B/C: PADCOL u32 (24 KB)
    float* xl = (float*)ubuf;                               // D: 128*55 f32 (27.5 KB)
    float* Wl = (float*)(ubuf + BNODES * GPAD * 4);         // D: 54*16 f32 (3.4 KB)

    int b = blockIdx.x;
    int t = threadIdx.x;
    int colbase = b * PADCOL;
    int row0 = b << BSHIFT;
    int nrows = min(BNODES, n - row0);

    for (int blk = t; blk < nbb; blk += LST) {
        st[blk] = lps[b * nbb + blk];
        en[blk] = lps[(b + 1) * nbb + blk];
    }
    if (t < BNODES) hist[t] = 0;
    __syncthreads();

    // --- A: per-node histogram over this bucket's cells ---
    int g = t >> 4, l = t & 15;             // 32 groups of 16 lanes
    for (int blk = g; blk < nbb; blk += (LST >> 4)) {
        int base = blk * per;
        int e = en[blk];
        for (int k = st[blk] + l; k < e; k += 16)
            atomicAdd(&hist[binned[base + k] & (BNODES - 1)], 1);
    }
    __syncthreads();
    if (t < BNODES) scn[t] = hist[t];
    __syncthreads();
    for (int d = 1; d < BNODES; d <<= 1) {
        int v = (t < BNODES && t >= d) ? scn[t - d] : 0;
        __syncthreads();
        if (t < BNODES) scn[t] += v;
        __syncthreads();
    }
    float di = 0.0f;
    if (t < BNODES) {
        int excl = scn[t] - hist[t];
        cur[t] = excl;
        int node = row0 + t;
        di = rsqrtf((float)hist[t] + 1.0f);
        if (node < n) {
            cs[node] = colbase + excl;
            ce[node] = colbase + excl + hist[t];
            dinv[node] = di;
        }
    }
    __syncthreads();
    // --- B: placement into LDS stage ---
    for (int blk = g; blk < nbb; blk += (LST >> 4)) {
        int base = blk * per;
        int e = en[blk];
        for (int k = st[blk] + l; k < e; k += 16) {
            unsigned int p = binned[base + k];
            int pos = atomicAdd(&cur[p & (BNODES - 1)], 1);
            unsigned int sv = p >> BSHIFT;
            if (pos < PADCOL) stage[pos] = sv;
            else col[colbase + pos] = sv;   // statistically-never overflow
        }
    }
    __syncthreads();
    // --- C: coalesced flush ---
    int len = scn[BNODES - 1];
    if (len > PADCOL) len = PADCOL;
    for (int k = t; k < len; k += LST) col[colbase + k] = stage[k];
    __syncthreads();
    // --- D: reuse ubuf as xl/Wl; stage x + W1; gemm tail ---
    const float* xb = x + (size_t)row0 * FIN;
    int tot = nrows * FIN;
    for (int i4 = t; i4 < (tot >> 2); i4 += LST) {
        float4 v = ((const float4*)xb)[i4];
        int i = i4 << 2;
        int r = i / FIN;
        int c = i - r * FIN;
#pragma unroll
        for (int u = 0; u < 4; ++u) {
            int cc = c + u, rr = r;
            if (cc >= FIN) { cc -= FIN; ++rr; }
            xl[rr * GPAD + cc] = (&v.x)[u];
        }
    }
    for (int i = (tot & ~3) + t; i < tot; i += LST) {
        int r = i / FIN;
        xl[r * GPAD + (i - r * FIN)] = xb[i];
    }
    for (int k = t; k < FIN * HDIM; k += LST) Wl[k] = W1[k];
    __syncthreads();
    if (t < nrows) {
        const float* xr = &xl[t * GPAD];
        float acc[HDIM];
#pragma unroll
        for (int j = 0; j < HDIM; ++j) acc[j] = 0.0f;
#pragma unroll
        for (int k = 0; k < FIN; ++k) {
            float xv = xr[k];
#pragma unroll
            for (int j = 0; j < HDIM; ++j)
                acc[j] = fmaf(xv, Wl[k * HDIM + j], acc[j]);
        }
        __half2 hh[8];
#pragma unroll
        for (int j = 0; j < 8; ++j)
            hh[j] = __floats2half2_rn(di * acc[2 * j], di * acc[2 * j + 1]);
        uint4* yo = (uint4*)(hA + ((size_t)(row0 + t) << 4));
        yo[0] = *(uint4*)&hh[0];
        yo[1] = *(uint4*)&hh[4];
    }
}

// ---------------------------------------------------------------------------
// Gather: 8 lanes per node (2 halves x 4 quarters). hs fp16, L2-resident.
// Each half sums alternating neighbors; halves combine via shfl_xor(4).
//   r = relu(dinv_i * (self + sum) + bias)
//   FUSE_W2: outh[i] = fp16(dinv_i * (r @ W2));  else out4[i] = r (f32)
// ---------------------------------------------------------------------------
__device__ __forceinline__ float4 ld_h4(const __half* __restrict__ hsh,
                                        unsigned int node, int q) {
    uint2 u = *(const uint2*)(hsh + ((size_t)node << 4) + (q << 2));
    __half2 a = *(__half2*)&u.x;
    __half2 b = *(__half2*)&u.y;
    float2 fa = __half22float2(a);
    float2 fb = __half22float2(b);
    return make_float4(fa.x, fa.y, fb.x, fb.y);
}

template <bool FUSE_W2>
__global__ void gather_kernel(const unsigned int* __restrict__ col,
                              const int* __restrict__ cs, const int* __restrict__ ce,
                              const __half* __restrict__ hsh, const float* __restrict__ dinv,
                              const float* __restrict__ bias, const float* __restrict__ W2,
                              __half* __restrict__ outh, float4* __restrict__ out4, int n) {
    __shared__ float4 W2l[HDIM * 4];   // W2l[jj*4+q] = W2[jj][4q..4q+3]
    if constexpr (FUSE_W2) {
        for (int t = threadIdx.x; t < HDIM * 4; t += blockDim.x)
            W2l[t] = ((const float4*)W2)[t];
        __syncthreads();
    }
    int idx = blockIdx.x * blockDim.x + threadIdx.x;
    int i = idx >> 3;
    int sub = idx & 7;
    int q = sub & 3;
    int h = sub >> 2;
    if (i >= n) return;
    int k0 = cs[i], k1 = ce[i];

    float4 acc = (h == 0) ? ld_h4(hsh, (unsigned int)i, q)   // self-loop on half 0
                          : make_float4(0.f, 0.f, 0.f, 0.f);
    int k = k0 + h;
    for (; k + 14 < k1; k += 16) {
        unsigned int s[8];
#pragma unroll
        for (int u = 0; u < 8; ++u) s[u] = col[k + 2 * u];
        float4 hv[8];
#pragma unroll
        for (int u = 0; u < 8; ++u) hv[u] = ld_h4(hsh, s[u], q);
#pragma unroll
        for (int u = 0; u < 8; ++u) {
            acc.x += hv[u].x; acc.y += hv[u].y; acc.z += hv[u].z; acc.w += hv[u].w;
        }
    }
    for (; k + 6 < k1; k += 8) {
        unsigned int s[4];
#pragma unroll
        for (int u = 0; u < 4; ++u) s[u] = col[k + 2 * u];
        float4 hv[4];
#pragma unroll
        for (int u = 0; u < 4; ++u) hv[u] = ld_h4(hsh, s[u], q);
#pragma unroll
        for (int u = 0; u < 4; ++u) {
            acc.x += hv[u].x; acc.y += hv[u].y; acc.z += hv[u].z; acc.w += hv[u].w;
        }
    }
    for (; k < k1; k += 2) {
        float4 hv = ld_h4(hsh, col[k], q);
        acc.x += hv.x; acc.y += hv.y; acc.z += hv.z; acc.w += hv.w;
    }
    // combine the two halves (partner = lane ^ 4)
    acc.x += __shfl_xor(acc.x, 4);
    acc.y += __shfl_xor(acc.y, 4);
    acc.z += __shfl_xor(acc.z, 4);
    acc.w += __shfl_xor(acc.w, 4);

    float di = dinv[i];
    float4 b4 = ((const float4*)bias)[q];
    float4 r;
    r.x = fmaxf(fmaf(di, acc.x, b4.x), 0.0f);
    r.y = fmaxf(fmaf(di, acc.y, b4.y), 0.0f);
    r.z = fmaxf(fmaf(di, acc.z, b4.z), 0.0f);
    r.w = fmaxf(fmaf(di, acc.w, b4.w), 0.0f);

    if constexpr (FUSE_W2) {
        int lane = threadIdx.x & 63;
        int base = lane & ~7;              // node's first lane (h=0, q=0)
        float4 o = make_float4(0.f, 0.f, 0.f, 0.f);
#pragma unroll
        for (int p = 0; p < 4; ++p) {      // lane base+p holds r for jj = 4p..4p+3
            float rx = __shfl(r.x, base + p, 64);
            float ry = __shfl(r.y, base + p, 64);
            float rz = __shfl(r.z, base + p, 64);
            float rw = __shfl(r.w, base + p, 64);
            float4 w0 = W2l[(p * 4 + 0) * 4 + q];
            float4 w1 = W2l[(p * 4 + 1) * 4 + q];
            float4 w2 = W2l[(p * 4 + 2) * 4 + q];
            float4 w3 = W2l[(p * 4 + 3) * 4 + q];
            o.x = fmaf(rx, w0.x, fmaf(ry, w1.x, fmaf(rz, w2.x, fmaf(rw, w3.x, o.x))));
            o.y = fmaf(rx, w0.y, fmaf(ry, w1.y, fmaf(rz, w2.y, fmaf(rw, w3.y, o.y))));
            o.z = fmaf(rx, w0.z, fmaf(ry, w1.z, fmaf(rz, w2.z, fmaf(rw, w3.z, o.z))));
            o.w = fmaf(rx, w0.w, fmaf(ry, w1.w, fmaf(rz, w2.w, fmaf(rw, w3.w, o.w))));
        }
        if (h == 0) {
            __half2 o01 = __floats2half2_rn(di * o.x, di * o.y);
            __half2 o23 = __floats2half2_rn(di * o.z, di * o.w);
            uint2 pk;
            pk.x = *(unsigned int*)&o01;
            pk.y = *(unsigned int*)&o23;
            *(uint2*)(outh + ((size_t)i << 4) + (q << 2)) = pk;
        }
    } else {
        if (h == 0) out4[(size_t)i * 4 + q] = r;
    }
}

extern "C" void kernel_launch(void* const* d_in, const int* in_sizes, int n_in,
                              void* d_out, int out_size, void* d_ws, size_t ws_size,
                              hipStream_t stream) {
    const float* x  = (const float*)d_in[0];   // [n, 54]
    const int*   ei = (const int*)d_in[1];     // [2, E]
    const float* W1 = (const float*)d_in[2];   // [54, 16]
    const float* b1 = (const float*)d_in[3];   // [16]
    const float* W2 = (const float*)d_in[4];   // [16, 16]
    const float* b2 = (const float*)d_in[5];   // [16]
    float* out = (float*)d_out;

    const int E = in_sizes[1] / 2;             // 3,200,000
    const int n = in_sizes[0] / FIN;           // 100,000
    const int* src = ei;
    const int* dst = ei + E;
    const int nb = (n + BNODES - 1) >> BSHIFT; // 782 buckets

    // fill blocks: per-block range fits the 50 KB stage
    int nbb = (E + 12499) / 12500;             // 256 for E = 3.2M
    if (nbb > NBBMAX) nbb = NBBMAX;
    int per = (((E + nbb - 1) / nbb) + 3) & ~3;  // 12500, multiple of 4, <= FPE

    char* w = (char*)d_ws;
    auto take = [&](size_t bytes) { char* p = w; w += (bytes + 255) & ~(size_t)255; return p; };
    float* dinv = (float*)take((size_t)n * 4);
    int*   lps  = (int*)take((size_t)(nb + 1) * nbb * 4);
    int*   cs   = (int*)take((size_t)n * 4);
    int*   ce   = (int*)take((size_t)n * 4);
    unsigned int* binned = (unsigned int*)take((size_t)nbb * per * 4);
    __half* hA  = (__half*)take((size_t)n * HDIM * 2);   // must NOT alias binned
    __half* hB  = (__half*)take((size_t)n * HDIM * 2);
    unsigned int* col = (unsigned int*)take((size_t)nb * PADCOL * 4);

    const int B = 256;

    // --- build: fill (self-scanned) -> sort+gemm (CSR + dinv + hA) ---
    fill_binned_kernel<<<nbb, FBT, 0, stream>>>(src, dst, lps, binned, E, nb, nbb, per);
    sort_gemm_kernel<<<nb, LST, 0, stream>>>(binned, lps, x, W1, col, cs, ce, dinv,
                                             hA, n, nb, nbb, per);

    // --- layer 1 gather + relu + fused @W2 (pre-scaled, fp16) -> hB ---
    gather_kernel<true><<<(n * 8 + B - 1) / B, B, 0, stream>>>(
        col, cs, ce, hA, dinv, b1, W2, hB, nullptr, n);

    // --- layer 2 gather + bias + relu -> out (f32) ---
    gather_kernel<false><<<(n * 8 + B - 1) / B, B, 0, stream>>>(
        col, cs, ce, hB, dinv, b2, nullptr, nullptr, (float4*)out, n);
}